// Round 12
// baseline (417.274 us; speedup 1.0000x reference)
//
#include <hip/hip_runtime.h>
#include <hip/hip_bf16.h>

typedef unsigned short u16;
typedef __attribute__((ext_vector_type(8))) short bfrag;   // 8 x bf16 (4 VGPRs)
typedef __attribute__((ext_vector_type(4))) float ffrag;   // 4 x f32

// ---- problem constants ----
#define NWIN_TOT 1024      // B_ = 16 * 64 windows
#define NTOK 64            // tokens per window
#define CDIM 512
#define NHEAD 16
#define HDIM 32
#define NW 64              // mask windows

__device__ __forceinline__ u16 f2bf(float f) {
  union { float f; unsigned u; } v; v.f = f;
  unsigned r = v.u + 0x7fffu + ((v.u >> 16) & 1u);
  return (u16)(r >> 16);
}

__device__ __forceinline__ float bfhi2f(unsigned hi_bits) {  // bf16 in high 16 bits
  union { unsigned u; float f; } v; v.u = hi_bits; return v.f;
}

__device__ __forceinline__ ffrag mfma16(bfrag a, bfrag b, ffrag c) {
  return __builtin_amdgcn_mfma_f32_16x16x32_bf16(a, b, c, 0, 0, 0);
}

// async global->LDS, 16B per lane, linear LDS dest (wave base + lane*16)
__device__ __forceinline__ void gload16(const u16* src, u16* lds) {
  __builtin_amdgcn_global_load_lds(
      (const __attribute__((address_space(1))) unsigned int*)src,
      (__attribute__((address_space(3))) unsigned int*)lds, 16, 0, 0);
}

#define BAR() __builtin_amdgcn_s_barrier()
#define VMW(n) do { asm volatile("s_waitcnt vmcnt(" #n ")" ::: "memory"); \
                    __builtin_amdgcn_sched_barrier(0); } while (0)

// ---------------------------------------------------------------------------
// prep: x -> bf16; weights -> bf16; combined bias+mask table (bf16, row-major)
// ---------------------------------------------------------------------------
__global__ __launch_bounds__(256) void k_prep(const float* __restrict__ x,
                                              const float* __restrict__ qkv_w,
                                              const float* __restrict__ proj_w,
                                              const int*   __restrict__ rel_index,
                                              const float* __restrict__ rpb,
                                              const float* __restrict__ mask,
                                              u16* __restrict__ xb,
                                              u16* __restrict__ wq, u16* __restrict__ wp,
                                              u16* __restrict__ combB) {
  int i = blockIdx.x * 256 + threadIdx.x;
  if (i < 4194304) {            // x -> bf16, 8 elems/thread
    int e = i * 8;
    const float4* xp = reinterpret_cast<const float4*>(x + e);
    float4 lo = xp[0], hi = xp[1];
    union { u16 u[8]; bfrag v; } pk;
    pk.u[0] = f2bf(lo.x); pk.u[1] = f2bf(lo.y); pk.u[2] = f2bf(lo.z); pk.u[3] = f2bf(lo.w);
    pk.u[4] = f2bf(hi.x); pk.u[5] = f2bf(hi.y); pk.u[6] = f2bf(hi.z); pk.u[7] = f2bf(hi.w);
    *reinterpret_cast<bfrag*>(xb + e) = pk.v;
    return;
  }
  i -= 4194304;
  if (i < 786432) { wq[i] = f2bf(qkv_w[i]); return; }
  i -= 786432;
  if (i < 262144) { wp[i] = f2bf(proj_w[i]); return; }
  i -= 262144;
  {                              // combB
    int wh = i >> 12, rc = i & 4095;
    int w0 = wh >> 4, h = wh & 15;
    combB[i] = f2bf(rpb[rel_index[rc] * 16 + h] + mask[(w0 << 12) + rc]);
  }
}

// ---------------------------------------------------------------------------
// A-RESIDENT GEMM (flatmm style): block = 128 A-rows; the FULL A M-tile
// (128 x 512 bf16 = 128 KiB) is loaded to LDS ONCE (swizzled, one
// vmcnt(0)+barrier), then the block sweeps NT n-tiles of 128 cols.
// B fragments are read directly from global W (L2-hot, 1.5 MB) into
// registers -- NO LDS staging, NO barriers, NO cross-wave hazards in the
// main loop; the compiler software-pipelines the 8-step K-loop freely.
// 512 thr = 8 waves (2M x 4N): wave = 64 rows x 32 cols, acc[4][2].
// LDS swizzle: byte col ^ ((row&7)<<4) within each 128-B chunk of the
// 1024-B row (reads: 8 rows/16-lane group -> 2 lanes/bank = free).
// ---------------------------------------------------------------------------
template<int EPI>
__global__ __launch_bounds__(512, 1) void k_gemmA(const u16* __restrict__ A,
                                                  const u16* __restrict__ W,
                                                  const float* __restrict__ bias,
                                                  u16* __restrict__ qws, u16* __restrict__ kws,
                                                  u16* __restrict__ vws,
                                                  float* __restrict__ out) {
  constexpr int NT = (EPI == 0) ? 12 : 4;          // N / 128
  extern __shared__ __align__(16) u16 smem[];      // [128][512] bf16 = 128 KiB

  const int bid = blockIdx.x;                      // 512 blocks = M/128
  const int brow = bid << 7;

  const int tid = threadIdx.x;
  const int wv = tid >> 6, lane = tid & 63, c15 = lane & 15, g = lane >> 4;
  const int g4 = g * 4;
  const int wr = wv >> 2, wc = wv & 3;             // 2M x 4N wave grid
  const ffrag zf = {0.f, 0.f, 0.f, 0.f};
  const char* Asb = reinterpret_cast<const char*>(smem);

  // ---- stage full A tile: 65536 elems, 16 calls x 512 thr x 8 elems ----
#pragma unroll
  for (int cl = 0; cl < 16; ++cl) {
    int e = cl * 4096 + tid * 8;
    int row = e >> 9, cb = (e & 511) << 1;         // row, byte col
    int scol = (cb ^ ((row & 7) << 4)) >> 1;       // inverse-swizzled source col
    gload16(A + (size_t)(brow + row) * 512 + scol, smem + e);
  }
  VMW(0);
  BAR();                                           // the ONLY barrier

  for (int nt = 0; nt < NT; ++nt) {
    ffrag acc[4][2];
#pragma unroll
    for (int i = 0; i < 4; ++i) {
      acc[i][0] = zf; acc[i][1] = zf;
    }
    const u16* Wn = W + (size_t)(nt * 128 + wc * 32) * 512;

#pragma unroll 2
    for (int t = 0; t < 8; ++t) {
      bfrag a_[4][2], b_[2][2];
#pragma unroll
      for (int n = 0; n < 2; ++n)
#pragma unroll
        for (int ks = 0; ks < 2; ++ks)
          b_[n][ks] = *reinterpret_cast<const bfrag*>(
              Wn + (size_t)(n * 16 + c15) * 512 + t * 64 + ks * 32 + g * 8);
#pragma unroll
      for (int i = 0; i < 4; ++i) {
        int ra = wr * 64 + i * 16 + c15;
#pragma unroll
        for (int ks = 0; ks < 2; ++ks)
          a_[i][ks] = *reinterpret_cast<const bfrag*>(
              Asb + ra * 1024 + ((t * 128 + ks * 64 + g * 16) ^ ((ra & 7) << 4)));
      }
#pragma unroll
      for (int i = 0; i < 4; ++i)
#pragma unroll
        for (int n = 0; n < 2; ++n)
#pragma unroll
          for (int ks = 0; ks < 2; ++ks)
            acc[i][n] = mfma16(a_[i][ks], b_[n][ks], acc[i][n]);
    }

    // ---- epilogue for n-tile nt (R9-verified forms; 64-row waves) ----
    if (EPI == 0) {
      const float SCALE = 0.17677669529663687f;    // 32^-0.5
      const int win = (brow >> 6) + wr;            // wave rows = one window
#pragma unroll
      for (int n = 0; n < 2; ++n) {
        int c = nt * 128 + wc * 32 + n * 16 + c15; // 0..1535
        float bz = bias[c];
        int which = c >> 9;                        // wave-uniform: 0=q 1=k 2=v
        int cq = c & 511, h = cq >> 5, d = cq & 31;
        size_t slab = ((size_t)(win * NHEAD + h)) << 11;
        if (which == 2) {
          u16* vp = vws + slab + (d << 6);
#pragma unroll
          for (int i = 0; i < 4; ++i) {
            int tok0 = i * 16 + g4;
            union { u16 u[4]; uint2 v; } pk;
#pragma unroll
            for (int r = 0; r < 4; ++r) pk.u[r] = f2bf(acc[i][n][r] + bz);
            *reinterpret_cast<uint2*>(vp + tok0) = pk.v;
          }
        } else {
          const float s2 = (which == 0) ? SCALE : 1.0f;
          u16* qp = ((which == 0) ? qws : kws) + slab + d;
#pragma unroll
          for (int i = 0; i < 4; ++i)
#pragma unroll
            for (int r = 0; r < 4; ++r)
              qp[(i * 16 + g4 + r) << 5] = f2bf((acc[i][n][r] + bz) * s2);
        }
      }
    } else {
#pragma unroll
      for (int n = 0; n < 2; ++n) {
        int c = nt * 128 + wc * 32 + n * 16 + c15;
        float bz = bias[c];
        float* po = out + (size_t)(brow + wr * 64) * CDIM + c;
#pragma unroll
        for (int i = 0; i < 4; ++i)
#pragma unroll
          for (int r = 0; r < 4; ++r)
            po[(size_t)(i * 16 + g4 + r) * CDIM] = acc[i][n][r] + bz;
      }
    }
  }
}

// ---------------------------------------------------------------------------
// attention (R6): 1 wave per (window, head). S^T = mfma(K,Q); softmax in-lane
// +2shfl; combB bias; P -> swizzled LDS -> A-frags; PV via vT; y restaged
// through LDS [64][136] for coalesced 256B-row stores.
// ---------------------------------------------------------------------------
__global__ __launch_bounds__(256) void k_attn(const u16* __restrict__ qws,
                                              const u16* __restrict__ kws,
                                              const u16* __restrict__ vws,
                                              const u16* __restrict__ combB,
                                              u16* __restrict__ yws) {
  __shared__ __align__(16) u16 plds[4][NTOK * NTOK];  // 8 KiB per wave; reused for y
  const int tid = threadIdx.x, w = tid >> 6, lane = tid & 63;
  const int c15 = lane & 15, g = lane >> 4, g4 = g * 4;
  const int p = blockIdx.x * 4 + w;
  const int b = p >> 4, h = p & 15;

  const u16* qb_ = qws + (size_t)p * (NTOK * HDIM);
  const u16* kb_ = kws + (size_t)p * (NTOK * HDIM);
  bfrag qa[4], ka[4];
#pragma unroll
  for (int t = 0; t < 4; ++t) {
    qa[t] = *reinterpret_cast<const bfrag*>(qb_ + (t * 16 + c15) * HDIM + g * 8);
    ka[t] = *reinterpret_cast<const bfrag*>(kb_ + (t * 16 + c15) * HDIM + g * 8);
  }

  const u16* cB = combB + ((size_t)(((b & (NW - 1)) << 4) + h) << 12);  // [row][col]
  u16* pl = plds[w];
  const ffrag zf = {0.f, 0.f, 0.f, 0.f};

#pragma unroll
  for (int it = 0; it < 4; ++it) {
    int row = it * 16 + c15;           // score row
    float l[4][4];
    float mx = -3.0e38f;
#pragma unroll
    for (int jt = 0; jt < 4; ++jt) {
      ffrag s = mfma16(ka[jt], qa[it], zf);   // S^T tile: D[4g+r][c15]
      uint2 cw = *reinterpret_cast<const uint2*>(cB + row * 64 + jt * 16 + g4);
      l[jt][0] = s[0] + bfhi2f(cw.x << 16);
      l[jt][1] = s[1] + bfhi2f(cw.x & 0xffff0000u);
      l[jt][2] = s[2] + bfhi2f(cw.y << 16);
      l[jt][3] = s[3] + bfhi2f(cw.y & 0xffff0000u);
      mx = fmaxf(mx, fmaxf(fmaxf(l[jt][0], l[jt][1]), fmaxf(l[jt][2], l[jt][3])));
    }
    mx = fmaxf(mx, __shfl_xor(mx, 16));
    mx = fmaxf(mx, __shfl_xor(mx, 32));
    float sum = 0.f;
#pragma unroll
    for (int jt = 0; jt < 4; ++jt)
#pragma unroll
      for (int r = 0; r < 4; ++r) {
        float e = __expf(l[jt][r] - mx);
        l[jt][r] = e;
        sum += e;
      }
    sum += __shfl_xor(sum, 16);
    sum += __shfl_xor(sum, 32);
    float inv = 1.0f / sum;
#pragma unroll
    for (int jt = 0; jt < 4; ++jt) {
      union { u16 u[4]; uint2 v; } pk;
#pragma unroll
      for (int r = 0; r < 4; ++r) pk.u[r] = f2bf(l[jt][r] * inv);
      int off = row * 64 + ((jt * 16 + g4) ^ ((row & 7) << 3));
      *reinterpret_cast<uint2*>(&pl[off]) = pk.v;
    }
  }
  __syncthreads();

  const u16* vb_ = vws + (size_t)p * (HDIM * NTOK);
  ffrag o0[4] = {zf, zf, zf, zf}, o1[4] = {zf, zf, zf, zf};
#pragma unroll
  for (int ks = 0; ks < 2; ++ks) {
    bfrag vf0 = *reinterpret_cast<const bfrag*>(vb_ + c15 * NTOK + ks * 32 + g * 8);
    bfrag vf1 = *reinterpret_cast<const bfrag*>(vb_ + (16 + c15) * NTOK + ks * 32 + g * 8);
#pragma unroll
    for (int i = 0; i < 4; ++i) {
      int prow = i * 16 + c15;
      bfrag pa = *reinterpret_cast<const bfrag*>(
          &pl[prow * 64 + ((ks * 32 + g * 8) ^ ((prow & 7) << 3))]);
      o0[i] = mfma16(pa, vf0, o0[i]);
      o1[i] = mfma16(pa, vf1, o1[i]);
    }
  }
  __syncthreads();                                 // all waves done reading P

  // y -> LDS [64][136] (padded), then block-cooperative coalesced store
  u16* yl = &plds[0][0];
#pragma unroll
  for (int i = 0; i < 4; ++i)
#pragma unroll
    for (int r = 0; r < 4; ++r) {
      int tok = i * 16 + g4 + r;
      yl[tok * 136 + w * 32 + c15] = f2bf(o0[i][r]);
      yl[tok * 136 + w * 32 + 16 + c15] = f2bf(o1[i][r]);
    }
  __syncthreads();
  {
    const int b2 = blockIdx.x >> 2;
    const int h0 = (blockIdx.x * 4) & 15;          // first head of block
    int row = tid >> 2, seg = tid & 3;             // 64 rows x 4 segs of 32 elems
    const u16* src = yl + row * 136 + seg * 32;
    u16* dst = yws + ((size_t)b2 * NTOK + row) * CDIM + h0 * HDIM + seg * 32;
    bfrag v0 = *(const bfrag*)(src);
    bfrag v1 = *(const bfrag*)(src + 8);
    bfrag v2 = *(const bfrag*)(src + 16);
    bfrag v3 = *(const bfrag*)(src + 24);
    *(bfrag*)(dst) = v0;
    *(bfrag*)(dst + 8) = v1;
    *(bfrag*)(dst + 16) = v2;
    *(bfrag*)(dst + 24) = v3;
  }
}

// ---------------------------------------------------------------------------
extern "C" void kernel_launch(void* const* d_in, const int* in_sizes, int n_in,
                              void* d_out, int out_size, void* d_ws, size_t ws_size,
                              hipStream_t stream) {
  const float* x      = (const float*)d_in[0];
  const float* mask   = (const float*)d_in[1];
  const float* qkv_w  = (const float*)d_in[2];
  const float* qkv_b  = (const float*)d_in[3];
  const float* proj_w = (const float*)d_in[4];
  const float* proj_b = (const float*)d_in[5];
  const float* rpb    = (const float*)d_in[6];
  const int*   rel    = (const int*)d_in[7];
  float* out = (float*)d_out;

  char* ws = (char*)d_ws;
  constexpr size_t SZ_QKV = (size_t)NWIN_TOT * NHEAD * NTOK * HDIM * 2;  // 64 MiB each
  u16* qws = (u16*)(ws);
  u16* kws = (u16*)(ws + SZ_QKV);
  u16* vws = (u16*)(ws + 2 * SZ_QKV);
  u16* xb  = (u16*)(ws + 3 * SZ_QKV);   // x as bf16; dead after k_gemmA<0> ...
  u16* yws = xb;                        // ... so yws aliases it (written in k_attn)
  u16* wq  = (u16*)(ws + 4 * SZ_QKV);
  u16* wp  = (u16*)(ws + 4 * SZ_QKV + 1572864);
  u16* combB = (u16*)(ws + 4 * SZ_QKV + 1572864 + 524288);  // 8 MiB

  hipFuncSetAttribute((const void*)k_gemmA<0>,
                      hipFuncAttributeMaxDynamicSharedMemorySize, 131072);
  hipFuncSetAttribute((const void*)k_gemmA<1>,
                      hipFuncAttributeMaxDynamicSharedMemorySize, 131072);

  k_prep<<<dim3(36864), dim3(256), 0, stream>>>(x, qkv_w, proj_w, rel, rpb, mask,
                                                xb, wq, wp, combB);
  k_gemmA<0><<<dim3(512), dim3(512), 131072, stream>>>(xb, wq, qkv_b, qws, kws, vws, nullptr);
  k_attn<<<dim3(NWIN_TOT * NHEAD / 4), dim3(256), 0, stream>>>(qws, kws, vws, combB, yws);
  k_gemmA<1><<<dim3(512), dim3(512), 131072, stream>>>(yws, wp, proj_b, nullptr, nullptr, nullptr, out);
}